// Round 17
// baseline (283.124 us; speedup 1.0000x reference)
//
#include <hip/hip_runtime.h>
#include <cstdint>
#include <cstddef>

// Problem constants (fixed by reference)
#define NN 100000          // nodes
#define EE 800000          // edges
#define HD 128             // hidden dim
#define OD 64              // out dim
#define CAP 64             // bucket capacity per node (P(deg>64) ~ 0 for Poisson(8))
#define WPL 400000         // dropout mask words per layer = NN*HD/32
#define ALDS 136           // padded act-tile stride (bf16 elems)

typedef __attribute__((ext_vector_type(8))) short s16x8;
typedef __attribute__((ext_vector_type(4))) float f32x4;
typedef __attribute__((ext_vector_type(8))) unsigned short u16x8;

// RNE float -> bf16
__device__ __forceinline__ unsigned short f2bf(float f) {
  unsigned u = __float_as_uint(f);
  return (unsigned short)((u + 0x7FFFu + ((u >> 16) & 1u)) >> 16);
}
__device__ __forceinline__ float bf2f(unsigned short v) {
  return __uint_as_float(((unsigned)v) << 16);
}

__host__ __device__ __forceinline__ unsigned rotl32(unsigned x, int r) {
#ifdef __HIP_DEVICE_COMPILE__
  return __builtin_amdgcn_alignbit(x, x, 32 - r);  // (x<<r)|(x>>(32-r)), 1 instr
#else
  return (x << r) | (x >> (32 - r));
#endif
}

// ---------------- Threefry-2x32 (20 rounds), bit-exact vs JAX ----------------
__host__ __device__ __forceinline__ void tf2x32(unsigned k0, unsigned k1,
                                                unsigned x0, unsigned x1,
                                                unsigned& o0, unsigned& o1) {
  unsigned ks2 = k0 ^ k1 ^ 0x1BD11BDAu;
#define TFR(r) { x0 += x1; x1 = rotl32(x1, (r)) ^ x0; }
  x0 += k0; x1 += k1;
  TFR(13) TFR(15) TFR(26) TFR(6)
  x0 += k1; x1 += ks2 + 1u;
  TFR(17) TFR(29) TFR(16) TFR(24)
  x0 += ks2; x1 += k0 + 2u;
  TFR(13) TFR(15) TFR(26) TFR(6)
  x0 += k0; x1 += k1 + 3u;
  TFR(17) TFR(29) TFR(16) TFR(24)
  x0 += k1; x1 += ks2 + 4u;
  TFR(13) TFR(15) TFR(26) TFR(6)
  x0 += ks2; x1 += k0 + 5u;
#undef TFR
  o0 = x0; o1 = x1;
}

// cast 8 fp32 -> 8 bf16 at flat chunk t (elems [t*8, t*8+8))
__device__ __forceinline__ void cast8(const float* __restrict__ x,
                                      unsigned short* __restrict__ xb, int t) {
  const float4* p = (const float4*)x + (size_t)t * 2;
  float4 v0 = p[0], v1 = p[1];
  u16x8 r;
  r[0] = f2bf(v0.x); r[1] = f2bf(v0.y); r[2] = f2bf(v0.z); r[3] = f2bf(v0.w);
  r[4] = f2bf(v1.x); r[5] = f2bf(v1.y); r[6] = f2bf(v1.z); r[7] = f2bf(v1.w);
  *((u16x8*)xb + t) = r;
}

// ---------------- Weight casts + fill zeroing (absorbs the memset) ------------
// Wb pre-swizzled: elem' = elem ^ ((row&7)<<3)  (byte ^= (row&7)<<4)
__global__ __launch_bounds__(256) void k_castw(const float* __restrict__ Wl,
                                               const float* __restrict__ Wr,
                                               const float* __restrict__ Wo,
                                               unsigned short* __restrict__ Wb,
                                               unsigned short* __restrict__ Wob,
                                               int* __restrict__ fill) {
  int t = blockIdx.x * 256 + threadIdx.x;
  if (t < NN) fill[t] = 0;
  if (t < 3 * 128 * 256) {
    int l = t >> 15;
    int rem = t & 32767;
    int n = rem >> 8;
    int k = rem & 255;
    float w = (k < 128) ? Wl[(l << 14) + (n << 7) + k] : Wr[(l << 14) + (n << 7) + (k - 128)];
    int sw = rem ^ ((n & 7) << 3);
    Wb[(l << 15) + sw] = f2bf(w);
  } else {
    int t3 = t - 3 * 128 * 256;
    if (t3 < OD * 128) Wob[t3] = f2bf(Wo[t3]);
  }
}

// ---------------- Single edge pass, 2 edges/thread ---------------------------
// 3125 blocks x 128 threads = 400000 threads = 6250 full waves.
// TWO independent atomic->scatter chains per thread (2x MLP on the latency
// chain that dominates this kernel); both atomics issued first, both stores
// last; 4x cast8 + 32 threefry (mask1, 2048 bits/wave) hide in between.
__global__ __launch_bounds__(128) void k_fill2(const int* __restrict__ ei,
                                               int* __restrict__ fill,
                                               int* __restrict__ bucket,
                                               unsigned long long* __restrict__ mask1,
                                               unsigned mk0, unsigned mk1,
                                               const float* __restrict__ x,
                                               unsigned short* __restrict__ xb) {
  const int t = blockIdx.x * 128 + threadIdx.x;   // < 400000 always
  const int e0 = t;
  const int e1 = t + 400000;
  unsigned s0 = (unsigned)ei[e0];
  unsigned d0 = (unsigned)ei[EE + e0];
  unsigned s1 = (unsigned)ei[e1];
  unsigned d1 = (unsigned)ei[EE + e1];
  if (s0 >= NN) s0 = 0;
  if (d0 >= NN) d0 = 0;
  if (s1 >= NN) s1 = 0;
  if (d1 >= NN) d1 = 0;
  int p0 = atomicAdd(&fill[d0], 1);               // issue both chains early...
  int p1 = atomicAdd(&fill[d1], 1);
  cast8(x, xb, t);                                // x-cast: 4 chunks/thread
  cast8(x, xb, t + 400000);
  cast8(x, xb, t + 800000);
  cast8(x, xb, t + 1200000);
  // mask1: wave covers 2048 bits at wave*2048 (32 tf, compile-time unrolled)
  {
    const int wave = t >> 6;
    const int lane = t & 63;
    const unsigned base = (unsigned)wave * 2048u + (unsigned)lane;
#pragma unroll
    for (int c = 0; c < 32; ++c) {
      unsigned r0, r1;
      tf2x32(mk0, mk1, 0u, base + (unsigned)(c << 6), r0, r1);
      unsigned long long m = __ballot(((r0 ^ r1) & 0x80000000u) == 0u);
      if (lane == 0) mask1[wave * 32 + c] = m;
    }
  }
  if (p0 < CAP) bucket[d0 * CAP + p0] = (int)s0;  // ...consume late
  if (p1 < CAP) bucket[d1 * CAP + p1] = (int)s1;
}

// ---------------- Mean aggregation from buckets (+ compile-time mask gen) -----
// QUARTER-wave per node (4 nodes/wave, 25000 waves), 16B u16x8 gathers,
// 4 streams in flight per quarter (16/wave), VGPR < 64. MCNT compile-time
// so the threefry chains unroll and interleave.
template<int MCNT>
__global__ __launch_bounds__(256) void k_aggb(const unsigned short* __restrict__ xb,
                                              const int* __restrict__ bucket,
                                              const int* __restrict__ fill,
                                              unsigned short* __restrict__ aggb,
                                              unsigned long long* __restrict__ maskW,
                                              unsigned mk0, unsigned mk1) {
  const int w = (blockIdx.x * 256 + threadIdx.x) >> 6;  // wave 0..24999
  const int lane = threadIdx.x & 63;
  const int q = lane >> 4;        // quarter 0..3
  const int ql = lane & 15;       // lane within quarter (col slice)
  const int qb = q << 4;
  const int n = (w << 2) + q;     // node, < 100000 always

  const int degf = fill[n];
  const int deg = (degf < CAP) ? degf : CAP;
  int idx = (ql < deg) ? bucket[n * CAP + ql] : 0;  // first 16 bucket entries
  const float sc = (degf > 0) ? 1.0f / (float)degf : 0.0f;  // IEEE div, matches ref

  if (MCNT > 0) {
    const unsigned base = (unsigned)w * 512u + (unsigned)lane;
#pragma unroll
    for (int c = 0; c < MCNT; ++c) {
      unsigned r0, r1;
      tf2x32(mk0, mk1, 0u, base + (unsigned)(c << 6), r0, r1);
      unsigned long long m = __ballot(((r0 ^ r1) & 0x80000000u) == 0u);
      if (lane == 0) maskW[(w << 3) + c] = m;
    }
  }

  const u16x8* xb8 = (const u16x8*)xb;   // row = 16 x u16x8
  float a0[8], a1[8], a2[8], a3[8];
#pragma unroll
  for (int k = 0; k < 8; ++k) { a0[k] = 0.f; a1[k] = 0.f; a2[k] = 0.f; a3[k] = 0.f; }

  const int dcap = (deg < 16) ? deg : 16;
  int i0 = 0;
  for (; i0 + 4 <= dcap; i0 += 4) {  // 4 gathers in flight per quarter
    int j0 = __shfl(idx, qb + i0);
    int j1 = __shfl(idx, qb + i0 + 1);
    int j2 = __shfl(idx, qb + i0 + 2);
    int j3 = __shfl(idx, qb + i0 + 3);
    u16x8 v0 = xb8[(size_t)j0 * 16 + ql];
    u16x8 v1 = xb8[(size_t)j1 * 16 + ql];
    u16x8 v2 = xb8[(size_t)j2 * 16 + ql];
    u16x8 v3 = xb8[(size_t)j3 * 16 + ql];
#pragma unroll
    for (int k = 0; k < 8; ++k) {
      a0[k] += bf2f(v0[k]); a1[k] += bf2f(v1[k]);
      a2[k] += bf2f(v2[k]); a3[k] += bf2f(v3[k]);
    }
  }
  // remainder (up to 3), guarded per-stream (exec-masked, loads still overlap)
  {
    const int rem = dcap - i0;
    int j0 = __shfl(idx, qb + (i0 & 15));
    int j1 = __shfl(idx, qb + ((i0 + 1) & 15));
    int j2 = __shfl(idx, qb + ((i0 + 2) & 15));
    if (rem > 0) {
      u16x8 v = xb8[(size_t)j0 * 16 + ql];
#pragma unroll
      for (int k = 0; k < 8; ++k) a0[k] += bf2f(v[k]);
    }
    if (rem > 1) {
      u16x8 v = xb8[(size_t)j1 * 16 + ql];
#pragma unroll
      for (int k = 0; k < 8; ++k) a1[k] += bf2f(v[k]);
    }
    if (rem > 2) {
      u16x8 v = xb8[(size_t)j2 * 16 + ql];
#pragma unroll
      for (int k = 0; k < 8; ++k) a2[k] += bf2f(v[k]);
    }
  }
  // deg in (16, 64]: uniform-address loads per quarter (~0.3% of nodes)
  for (int i = 16; i < deg; ++i) {
    int sX = bucket[n * CAP + i];
    u16x8 v = xb8[(size_t)sX * 16 + ql];
#pragma unroll
    for (int k = 0; k < 8; ++k) a3[k] += bf2f(v[k]);
  }

  u16x8 o;
#pragma unroll
  for (int k = 0; k < 8; ++k)
    o[k] = f2bf(((a0[k] + a1[k]) + (a2[k] + a3[k])) * sc);
  ((u16x8*)aggb)[(size_t)n * 16 + ql] = o;
}

// ---------------- Layer: bf16 MFMA GEMM, W staged in two 32KB LDS halves ------
// 64 rows/block (1563 blocks), 4 waves x 16 rows. LDS = 32KB -> ~5 blocks/CU.
// A-fragments for BOTH halves prefetched at entry (hide under W staging).
__global__ __launch_bounds__(256) void k_layer_mfma(
    const unsigned short* __restrict__ xin,   // [NN][128] bf16
    const unsigned short* __restrict__ aggb,  // [NN][128] bf16
    const unsigned short* __restrict__ Wb,    // [128][256] bf16, PRE-SWIZZLED
    const float* __restrict__ bias,           // [128] fp32
    const unsigned* __restrict__ mask,        // this layer's dropout bits
    unsigned short* __restrict__ xout) {
  __shared__ unsigned short Wlds[16384];      // 32 KB
  const int tid = threadIdx.x;
  const int lane = tid & 63;
  const int wv = tid >> 6;
  const int rbase = blockIdx.x * 64 + wv * 16;
  const int lr = lane & 15;
  const int lkq = lane >> 4;                  // 0..3
  const int rowg = lkq * 4;

  const f32x4* Wv = (const f32x4*)Wb;
  f32x4* dst = (f32x4*)Wlds;

  int n0 = rbase + lr;
  if (n0 >= NN) n0 = NN - 1;

  // prefetch all A fragments (issued before any LDS staging)
  s16x8 pa[4], px[4];
#pragma unroll
  for (int kfl = 0; kfl < 4; ++kfl) {
    const int kc = kfl * 32 + lkq * 8;
    pa[kfl] = *(const s16x8*)(aggb + (size_t)n0 * 128 + kc);
    px[kfl] = *(const s16x8*)(xin + (size_t)n0 * 128 + kc);
  }

  f32x4 acc[8];
#pragma unroll
  for (int j = 0; j < 8; ++j) acc[j] = (f32x4){0.f, 0.f, 0.f, 0.f};

  const char* WL = (const char*)Wlds;
#pragma unroll
  for (int half = 0; half < 2; ++half) {
    if (half) __syncthreads();   // all waves done reading previous half
#pragma unroll
    for (int it = 0; it < 8; ++it) {
      const int c = it * 256 + tid;
      dst[c] = Wv[((c >> 4) << 5) + (half << 4) + (c & 15)];
    }
    __syncthreads();
#pragma unroll
    for (int kfl = 0; kfl < 4; ++kfl) {
      s16x8 a0 = half ? px[kfl] : pa[kfl];
#pragma unroll
      for (int nf = 0; nf < 8; ++nf) {
        const int row = nf * 16 + lr;
        const int bo = (row << 8) + ((((kfl << 6) + (lkq << 4)) ^ ((row & 7) << 4)));
        s16x8 wfr = *(const s16x8*)(WL + bo);
        acc[nf] = __builtin_amdgcn_mfma_f32_16x16x32_bf16(wfr, a0, acc[nf], 0, 0, 0);
      }
    }
  }

  const int node = rbase + lr;
  if (node < NN) {
    const unsigned mbase = (unsigned)node * 4u;
#pragma unroll
    for (int nf = 0; nf < 8; ++nf) {
      const int colb = nf * 16 + rowg;
      const float4 bv = *(const float4*)(bias + colb);
      const unsigned mw = mask[mbase + (colb >> 5)];
      const unsigned sh = (unsigned)(colb & 31);
      float v0 = acc[nf][0] + bv.x;
      float v1 = acc[nf][1] + bv.y;
      float v2 = acc[nf][2] + bv.z;
      float v3 = acc[nf][3] + bv.w;
      v0 = (v0 > 0.f) ? v0 : 0.01f * v0;
      v1 = (v1 > 0.f) ? v1 : 0.01f * v1;
      v2 = (v2 > 0.f) ? v2 : 0.01f * v2;
      v3 = (v3 > 0.f) ? v3 : 0.01f * v3;
      ushort4 o;
      o.x = ((mw >> (sh + 0)) & 1u) ? f2bf(v0 + v0) : (unsigned short)0;
      o.y = ((mw >> (sh + 1)) & 1u) ? f2bf(v1 + v1) : (unsigned short)0;
      o.z = ((mw >> (sh + 2)) & 1u) ? f2bf(v2 + v2) : (unsigned short)0;
      o.w = ((mw >> (sh + 3)) & 1u) ? f2bf(v3 + v3) : (unsigned short)0;
      *(ushort4*)(xout + (size_t)node * 128 + colb) = o;
    }
  }
}

// ---------------- Fused layer 3 + final projection ----------------------------
__global__ __launch_bounds__(256) void k_layer3_final(
    const unsigned short* __restrict__ xin,   // [NN][128] bf16
    const unsigned short* __restrict__ aggb,  // [NN][128] bf16
    const unsigned short* __restrict__ Wb,    // layer-3 [128][256], PRE-SWIZZLED
    const float* __restrict__ bias,           // [128] fp32
    const unsigned* __restrict__ mask,        // layer-3 dropout bits
    const unsigned short* __restrict__ Wob,   // [64][128] bf16 (linear)
    const float* __restrict__ bo,             // [64]
    float* __restrict__ out) {
  __shared__ unsigned short smem[16384];      // 32 KB: W halves, then act tile
  const int tid = threadIdx.x;
  const int lane = tid & 63;
  const int wv = tid >> 6;
  const int rbase = blockIdx.x * 64 + wv * 16;
  const int lr = lane & 15;
  const int lkq = lane >> 4;                  // 0..3
  const int rowg = lkq * 4;

  const f32x4* Wv = (const f32x4*)Wb;
  f32x4* dst = (f32x4*)smem;

  int n0 = rbase + lr;
  if (n0 >= NN) n0 = NN - 1;

  // prefetch all A fragments
  s16x8 pa[4], px[4];
#pragma unroll
  for (int kfl = 0; kfl < 4; ++kfl) {
    const int kc = kfl * 32 + lkq * 8;
    pa[kfl] = *(const s16x8*)(aggb + (size_t)n0 * 128 + kc);
    px[kfl] = *(const s16x8*)(xin + (size_t)n0 * 128 + kc);
  }

  f32x4 acc[8];
#pragma unroll
  for (int j = 0; j < 8; ++j) acc[j] = (f32x4){0.f, 0.f, 0.f, 0.f};

  const char* WL = (const char*)smem;
#pragma unroll
  for (int half = 0; half < 2; ++half) {
    if (half) __syncthreads();
#pragma unroll
    for (int it = 0; it < 8; ++it) {
      const int c = it * 256 + tid;
      dst[c] = Wv[((c >> 4) << 5) + (half << 4) + (c & 15)];
    }
    __syncthreads();
#pragma unroll
    for (int kfl = 0; kfl < 4; ++kfl) {
      s16x8 a0 = half ? px[kfl] : pa[kfl];
#pragma unroll
      for (int nf = 0; nf < 8; ++nf) {
        const int row = nf * 16 + lr;
        const int bo2 = (row << 8) + ((((kfl << 6) + (lkq << 4)) ^ ((row & 7) << 4)));
        s16x8 wfr = *(const s16x8*)(WL + bo2);
        acc[nf] = __builtin_amdgcn_mfma_f32_16x16x32_bf16(wfr, a0, acc[nf], 0, 0, 0);
      }
    }
  }

  // epilogue -> act tile in LDS (reuse smem; W reads all complete after barrier)
  __syncthreads();
  {
    const int node = rbase + lr;
    const int nodec = (node < NN) ? node : (NN - 1);   // clamp for mask addressing
    const unsigned mbase = (unsigned)nodec * 4u;
    const int arow = wv * 16 + lr;                     // block-local act row
#pragma unroll
    for (int nf = 0; nf < 8; ++nf) {
      const int colb = nf * 16 + rowg;
      const float4 bv = *(const float4*)(bias + colb);
      const unsigned mw = mask[mbase + (colb >> 5)];
      const unsigned sh = (unsigned)(colb & 31);
      float v0 = acc[nf][0] + bv.x;
      float v1 = acc[nf][1] + bv.y;
      float v2 = acc[nf][2] + bv.z;
      float v3 = acc[nf][3] + bv.w;
      v0 = (v0 > 0.f) ? v0 : 0.01f * v0;
      v1 = (v1 > 0.f) ? v1 : 0.01f * v1;
      v2 = (v2 > 0.f) ? v2 : 0.01f * v2;
      v3 = (v3 > 0.f) ? v3 : 0.01f * v3;
      ushort4 o;
      o.x = ((mw >> (sh + 0)) & 1u) ? f2bf(v0 + v0) : (unsigned short)0;
      o.y = ((mw >> (sh + 1)) & 1u) ? f2bf(v1 + v1) : (unsigned short)0;
      o.z = ((mw >> (sh + 2)) & 1u) ? f2bf(v2 + v2) : (unsigned short)0;
      o.w = ((mw >> (sh + 3)) & 1u) ? f2bf(v3 + v3) : (unsigned short)0;
      *(ushort4*)(smem + arow * ALDS + colb) = o;
    }
  }
  __syncthreads();

  // final projection: each wave projects its own 16 rows from LDS
  f32x4 acc2[4];
#pragma unroll
  for (int j = 0; j < 4; ++j) acc2[j] = (f32x4){0.f, 0.f, 0.f, 0.f};

  const int arow = wv * 16 + lr;
#pragma unroll
  for (int kf = 0; kf < 4; ++kf) {
    const int kc = kf * 32 + lkq * 8;
    s16x8 a0 = *(const s16x8*)(smem + arow * ALDS + kc);
#pragma unroll
    for (int nf = 0; nf < 4; ++nf) {
      s16x8 wfr = *(const s16x8*)(Wob + (nf * 16 + lr) * 128 + kc);
      acc2[nf] = __builtin_amdgcn_mfma_f32_16x16x32_bf16(wfr, a0, acc2[nf], 0, 0, 0);
    }
  }

  const int node = rbase + lr;
  if (node < NN) {
#pragma unroll
    for (int nf = 0; nf < 4; ++nf) {
      const int colb = nf * 16 + rowg;
      const float4 bv = *(const float4*)(bo + colb);
      float4 o;
      o.x = acc2[nf][0] + bv.x;
      o.y = acc2[nf][1] + bv.y;
      o.z = acc2[nf][2] + bv.z;
      o.w = acc2[nf][3] + bv.w;
      *(float4*)(out + (size_t)node * 64 + colb) = o;
    }
  }
}

// ---------------- Host launch ----------------
extern "C" void kernel_launch(void* const* d_in, const int* in_sizes, int n_in,
                              void* d_out, int out_size, void* d_ws, size_t ws_size,
                              hipStream_t stream) {
  const float* x  = (const float*)d_in[0];
  const int*   ei = (const int*)d_in[1];
  const float* Wl = (const float*)d_in[2];
  const float* Wr = (const float*)d_in[3];
  const float* b  = (const float*)d_in[4];
  const float* Wo = (const float*)d_in[5];
  const float* bo = (const float*)d_in[6];
  float* out = (float*)d_out;

  char* wsp = (char*)d_ws;
  size_t off = 0;
  auto take = [&](size_t bytes) -> void* {
    off = (off + 255) & ~(size_t)255;
    void* p = wsp + off;
    off += bytes;
    return p;
  };
  unsigned short* xb0    = (unsigned short*)take((size_t)NN * 128 * 2);
  unsigned short* act1   = (unsigned short*)take((size_t)NN * 128 * 2);
  unsigned short* act2   = (unsigned short*)take((size_t)NN * 128 * 2);
  unsigned short* aggb   = (unsigned short*)take((size_t)NN * 128 * 2);
  unsigned short* Wb     = (unsigned short*)take((size_t)3 * 128 * 256 * 2);
  unsigned short* Wob    = (unsigned short*)take((size_t)OD * 128 * 2);
  unsigned*       masks  = (unsigned*)take((size_t)3 * WPL * 4);
  int*            bucket = (int*)take((size_t)NN * CAP * 4);
  int*            fill   = (int*)take((size_t)NN * 4);

  // ---- per-layer fold_in keys (host-side threefry: key(42) fold l) ----
  unsigned fk[3][2];
  for (int l = 0; l < 3; ++l) tf2x32(0u, 42u, 0u, (unsigned)l, fk[l][0], fk[l][1]);

  // ---- weight casts (+ fill zeroing) + single edge pass ----
  k_castw<<<(3 * 128 * 256 + OD * 128 + 255) / 256, 256, 0, stream>>>(Wl, Wr, Wo, Wb, Wob, fill);
  k_fill2<<<3125, 128, 0, stream>>>(ei, fill, bucket,
                                    (unsigned long long*)(masks + WPL),
                                    fk[1][0], fk[1][1], x, xb0);

  // ---- layers (mask0 in agg#1, mask2 in agg#2; compile-time MCNT) ----
  const int gemmBlocks = (NN + 63) / 64;    // 1563
  const int aggBlocks  = 6250;              // 25000 waves, 4 nodes/wave, exact fit

  k_aggb<8><<<aggBlocks, 256, 0, stream>>>(xb0, bucket, fill, aggb,
                                           (unsigned long long*)masks,
                                           fk[0][0], fk[0][1]);
  k_layer_mfma<<<gemmBlocks, 256, 0, stream>>>(xb0, aggb, Wb, b, masks, act1);

  k_aggb<8><<<aggBlocks, 256, 0, stream>>>(act1, bucket, fill, aggb,
                                           (unsigned long long*)(masks + 2 * WPL),
                                           fk[2][0], fk[2][1]);
  k_layer_mfma<<<gemmBlocks, 256, 0, stream>>>(act1, aggb, Wb + 32768, b + 128,
                                               masks + WPL, act2);

  k_aggb<0><<<aggBlocks, 256, 0, stream>>>(act2, bucket, fill, aggb,
                                           (unsigned long long*)0, 0u, 0u);
  k_layer3_final<<<gemmBlocks, 256, 0, stream>>>(act2, aggb, Wb + 65536, b + 256,
                                                 masks + 2 * WPL, Wob, bo, out);

  (void)in_sizes; (void)n_in; (void)out_size; (void)ws_size;
}

// Round 18
// 271.967 us; speedup vs baseline: 1.0410x; 1.0410x over previous
//
#include <hip/hip_runtime.h>
#include <cstdint>
#include <cstddef>

// Problem constants (fixed by reference)
#define NN 100000          // nodes
#define EE 800000          // edges
#define HD 128             // hidden dim
#define OD 64              // out dim
#define CAP 64             // bucket capacity per node (P(deg>64) ~ 0 for Poisson(8))
#define WPL 400000         // dropout mask words per layer = NN*HD/32
#define ALDS 136           // padded act-tile stride (bf16 elems)

typedef __attribute__((ext_vector_type(8))) short s16x8;
typedef __attribute__((ext_vector_type(4))) float f32x4;
typedef __attribute__((ext_vector_type(8))) unsigned short u16x8;

// RNE float -> bf16
__device__ __forceinline__ unsigned short f2bf(float f) {
  unsigned u = __float_as_uint(f);
  return (unsigned short)((u + 0x7FFFu + ((u >> 16) & 1u)) >> 16);
}
__device__ __forceinline__ float bf2f(unsigned short v) {
  return __uint_as_float(((unsigned)v) << 16);
}

__host__ __device__ __forceinline__ unsigned rotl32(unsigned x, int r) {
#ifdef __HIP_DEVICE_COMPILE__
  return __builtin_amdgcn_alignbit(x, x, 32 - r);  // (x<<r)|(x>>(32-r)), 1 instr
#else
  return (x << r) | (x >> (32 - r));
#endif
}

// ---------------- Threefry-2x32 (20 rounds), bit-exact vs JAX ----------------
__host__ __device__ __forceinline__ void tf2x32(unsigned k0, unsigned k1,
                                                unsigned x0, unsigned x1,
                                                unsigned& o0, unsigned& o1) {
  unsigned ks2 = k0 ^ k1 ^ 0x1BD11BDAu;
#define TFR(r) { x0 += x1; x1 = rotl32(x1, (r)) ^ x0; }
  x0 += k0; x1 += k1;
  TFR(13) TFR(15) TFR(26) TFR(6)
  x0 += k1; x1 += ks2 + 1u;
  TFR(17) TFR(29) TFR(16) TFR(24)
  x0 += ks2; x1 += k0 + 2u;
  TFR(13) TFR(15) TFR(26) TFR(6)
  x0 += k0; x1 += k1 + 3u;
  TFR(17) TFR(29) TFR(16) TFR(24)
  x0 += k1; x1 += ks2 + 4u;
  TFR(13) TFR(15) TFR(26) TFR(6)
  x0 += ks2; x1 += k0 + 5u;
#undef TFR
  o0 = x0; o1 = x1;
}

// 16 threefry+ballot -> one wave covers 1024 mask bits starting at wave*1024.
__device__ __forceinline__ void gen_mask_1024(unsigned long long* __restrict__ maskW,
                                              int wave, int lane,
                                              unsigned k0, unsigned k1) {
  const unsigned base = (unsigned)wave * 1024u + (unsigned)lane;
#pragma unroll
  for (int c = 0; c < 16; ++c) {
    unsigned r0, r1;
    tf2x32(k0, k1, 0u, base + (unsigned)(c << 6), r0, r1);
    unsigned long long m = __ballot(((r0 ^ r1) & 0x80000000u) == 0u);
    if (lane == 0) maskW[wave * 16 + c] = m;
  }
}

// cast 8 fp32 -> 8 bf16 at flat chunk t (elems [t*8, t*8+8))
__device__ __forceinline__ void cast8(const float* __restrict__ x,
                                      unsigned short* __restrict__ xb, int t) {
  const float4* p = (const float4*)x + (size_t)t * 2;
  float4 v0 = p[0], v1 = p[1];
  u16x8 r;
  r[0] = f2bf(v0.x); r[1] = f2bf(v0.y); r[2] = f2bf(v0.z); r[3] = f2bf(v0.w);
  r[4] = f2bf(v1.x); r[5] = f2bf(v1.y); r[6] = f2bf(v1.z); r[7] = f2bf(v1.w);
  *((u16x8*)xb + t) = r;
}

// ---------------- Weight casts + fill zeroing (absorbs the memset) ------------
// Wb pre-swizzled: elem' = elem ^ ((row&7)<<3)  (byte ^= (row&7)<<4)
__global__ __launch_bounds__(256) void k_castw(const float* __restrict__ Wl,
                                               const float* __restrict__ Wr,
                                               const float* __restrict__ Wo,
                                               unsigned short* __restrict__ Wb,
                                               unsigned short* __restrict__ Wob,
                                               int* __restrict__ fill) {
  int t = blockIdx.x * 256 + threadIdx.x;
  if (t < NN) fill[t] = 0;
  if (t < 3 * 128 * 256) {
    int l = t >> 15;
    int rem = t & 32767;
    int n = rem >> 8;
    int k = rem & 255;
    float w = (k < 128) ? Wl[(l << 14) + (n << 7) + k] : Wr[(l << 14) + (n << 7) + (k - 128)];
    int sw = rem ^ ((n & 7) << 3);
    Wb[(l << 15) + sw] = f2bf(w);
  } else {
    int t3 = t - 3 * 128 * 256;
    if (t3 < OD * 128) Wob[t3] = f2bf(Wo[t3]);
  }
}

// ---------------- Single edge pass: bucket fill + x-cast + mask1 --------------
// exact grid 3125 x 256 = 800000 (ballot needs all lanes active).
// r12-proven shape: 1 edge/thread (max TLP — r17's 2-edge/128-thr variant cut
// wave count in half and regressed), atomic issued first, consumed last.
__global__ __launch_bounds__(256) void k_fill2(const int* __restrict__ ei,
                                               int* __restrict__ fill,
                                               int* __restrict__ bucket,
                                               unsigned long long* __restrict__ mask1,
                                               unsigned mk0, unsigned mk1,
                                               const float* __restrict__ x,
                                               unsigned short* __restrict__ xb) {
  const int e = blockIdx.x * 256 + threadIdx.x;   // < EE always
  unsigned s = (unsigned)ei[e];
  unsigned d = (unsigned)ei[EE + e];
  if (s >= NN) s = 0;
  if (d >= NN) d = 0;
  int p = atomicAdd(&fill[d], 1);                  // issue early...
  cast8(x, xb, e);                                 // elems [0, 6.4M)
  cast8(x, xb, EE + e);                            // elems [6.4M, 12.8M)
  gen_mask_1024(mask1, e >> 6, e & 63, mk0, mk1);
  if (p < CAP) bucket[d * CAP + p] = (int)s;       // ...consume late
}

// ---------------- Mean aggregation from buckets (+ compile-time mask gen) -----
// QUARTER-wave per node (4 nodes/wave, 25000 waves), 16B u16x8 gathers,
// 4 streams in flight per quarter (16/wave), VGPR < 64. MCNT compile-time
// so the threefry chains unroll and interleave.
template<int MCNT>
__global__ __launch_bounds__(256) void k_aggb(const unsigned short* __restrict__ xb,
                                              const int* __restrict__ bucket,
                                              const int* __restrict__ fill,
                                              unsigned short* __restrict__ aggb,
                                              unsigned long long* __restrict__ maskW,
                                              unsigned mk0, unsigned mk1) {
  const int w = (blockIdx.x * 256 + threadIdx.x) >> 6;  // wave 0..24999
  const int lane = threadIdx.x & 63;
  const int q = lane >> 4;        // quarter 0..3
  const int ql = lane & 15;       // lane within quarter (col slice)
  const int qb = q << 4;
  const int n = (w << 2) + q;     // node, < 100000 always

  const int degf = fill[n];
  const int deg = (degf < CAP) ? degf : CAP;
  int idx = (ql < deg) ? bucket[n * CAP + ql] : 0;  // first 16 bucket entries
  const float sc = (degf > 0) ? 1.0f / (float)degf : 0.0f;  // IEEE div, matches ref

  if (MCNT > 0) {
    const unsigned base = (unsigned)w * 512u + (unsigned)lane;
#pragma unroll
    for (int c = 0; c < MCNT; ++c) {
      unsigned r0, r1;
      tf2x32(mk0, mk1, 0u, base + (unsigned)(c << 6), r0, r1);
      unsigned long long m = __ballot(((r0 ^ r1) & 0x80000000u) == 0u);
      if (lane == 0) maskW[(w << 3) + c] = m;
    }
  }

  const u16x8* xb8 = (const u16x8*)xb;   // row = 16 x u16x8
  float a0[8], a1[8], a2[8], a3[8];
#pragma unroll
  for (int k = 0; k < 8; ++k) { a0[k] = 0.f; a1[k] = 0.f; a2[k] = 0.f; a3[k] = 0.f; }

  const int dcap = (deg < 16) ? deg : 16;
  int i0 = 0;
  for (; i0 + 4 <= dcap; i0 += 4) {  // 4 gathers in flight per quarter
    int j0 = __shfl(idx, qb + i0);
    int j1 = __shfl(idx, qb + i0 + 1);
    int j2 = __shfl(idx, qb + i0 + 2);
    int j3 = __shfl(idx, qb + i0 + 3);
    u16x8 v0 = xb8[(size_t)j0 * 16 + ql];
    u16x8 v1 = xb8[(size_t)j1 * 16 + ql];
    u16x8 v2 = xb8[(size_t)j2 * 16 + ql];
    u16x8 v3 = xb8[(size_t)j3 * 16 + ql];
#pragma unroll
    for (int k = 0; k < 8; ++k) {
      a0[k] += bf2f(v0[k]); a1[k] += bf2f(v1[k]);
      a2[k] += bf2f(v2[k]); a3[k] += bf2f(v3[k]);
    }
  }
  // remainder (up to 3), guarded per-stream (exec-masked, loads still overlap)
  {
    const int rem = dcap - i0;
    int j0 = __shfl(idx, qb + (i0 & 15));
    int j1 = __shfl(idx, qb + ((i0 + 1) & 15));
    int j2 = __shfl(idx, qb + ((i0 + 2) & 15));
    if (rem > 0) {
      u16x8 v = xb8[(size_t)j0 * 16 + ql];
#pragma unroll
      for (int k = 0; k < 8; ++k) a0[k] += bf2f(v[k]);
    }
    if (rem > 1) {
      u16x8 v = xb8[(size_t)j1 * 16 + ql];
#pragma unroll
      for (int k = 0; k < 8; ++k) a1[k] += bf2f(v[k]);
    }
    if (rem > 2) {
      u16x8 v = xb8[(size_t)j2 * 16 + ql];
#pragma unroll
      for (int k = 0; k < 8; ++k) a2[k] += bf2f(v[k]);
    }
  }
  // deg in (16, 64]: uniform-address loads per quarter (~0.3% of nodes)
  for (int i = 16; i < deg; ++i) {
    int sX = bucket[n * CAP + i];
    u16x8 v = xb8[(size_t)sX * 16 + ql];
#pragma unroll
    for (int k = 0; k < 8; ++k) a3[k] += bf2f(v[k]);
  }

  u16x8 o;
#pragma unroll
  for (int k = 0; k < 8; ++k)
    o[k] = f2bf(((a0[k] + a1[k]) + (a2[k] + a3[k])) * sc);
  ((u16x8*)aggb)[(size_t)n * 16 + ql] = o;
}

// ---------------- Layer: bf16 MFMA GEMM, W staged in two 32KB LDS halves ------
// 64 rows/block (1563 blocks), 4 waves x 16 rows. LDS = 32KB -> ~5 blocks/CU.
// A loaded inside each half-loop (r12-proven; r16's prefetch added ~32 VGPR
// and regressed ~5us across the three layer dispatches).
__global__ __launch_bounds__(256) void k_layer_mfma(
    const unsigned short* __restrict__ xin,   // [NN][128] bf16
    const unsigned short* __restrict__ aggb,  // [NN][128] bf16
    const unsigned short* __restrict__ Wb,    // [128][256] bf16, PRE-SWIZZLED
    const float* __restrict__ bias,           // [128] fp32
    const unsigned* __restrict__ mask,        // this layer's dropout bits
    unsigned short* __restrict__ xout) {
  __shared__ unsigned short Wlds[16384];      // 32 KB
  const int tid = threadIdx.x;
  const int lane = tid & 63;
  const int wv = tid >> 6;
  const int rbase = blockIdx.x * 64 + wv * 16;
  const int lr = lane & 15;
  const int lkq = lane >> 4;                  // 0..3
  const int rowg = lkq * 4;

  const f32x4* Wv = (const f32x4*)Wb;
  f32x4* dst = (f32x4*)Wlds;

  f32x4 acc[8];
#pragma unroll
  for (int j = 0; j < 8; ++j) acc[j] = (f32x4){0.f, 0.f, 0.f, 0.f};

  int n0 = rbase + lr;
  if (n0 >= NN) n0 = NN - 1;

  const char* WL = (const char*)Wlds;
#pragma unroll
  for (int half = 0; half < 2; ++half) {
    if (half) __syncthreads();   // all waves done reading previous half
#pragma unroll
    for (int it = 0; it < 8; ++it) {
      const int c = it * 256 + tid;
      dst[c] = Wv[((c >> 4) << 5) + (half << 4) + (c & 15)];
    }
    __syncthreads();
    const unsigned short* A = half ? xin : aggb;
#pragma unroll
    for (int kfl = 0; kfl < 4; ++kfl) {
      const int kc = kfl * 32 + lkq * 8;
      s16x8 a0 = *(const s16x8*)(A + (size_t)n0 * 128 + kc);
#pragma unroll
      for (int nf = 0; nf < 8; ++nf) {
        const int row = nf * 16 + lr;
        const int bo = (row << 8) + ((((kfl << 6) + (lkq << 4)) ^ ((row & 7) << 4)));
        s16x8 wfr = *(const s16x8*)(WL + bo);
        acc[nf] = __builtin_amdgcn_mfma_f32_16x16x32_bf16(wfr, a0, acc[nf], 0, 0, 0);
      }
    }
  }

  const int node = rbase + lr;
  if (node < NN) {
    const unsigned mbase = (unsigned)node * 4u;
#pragma unroll
    for (int nf = 0; nf < 8; ++nf) {
      const int colb = nf * 16 + rowg;
      const float4 bv = *(const float4*)(bias + colb);
      const unsigned mw = mask[mbase + (colb >> 5)];
      const unsigned sh = (unsigned)(colb & 31);
      float v0 = acc[nf][0] + bv.x;
      float v1 = acc[nf][1] + bv.y;
      float v2 = acc[nf][2] + bv.z;
      float v3 = acc[nf][3] + bv.w;
      v0 = (v0 > 0.f) ? v0 : 0.01f * v0;
      v1 = (v1 > 0.f) ? v1 : 0.01f * v1;
      v2 = (v2 > 0.f) ? v2 : 0.01f * v2;
      v3 = (v3 > 0.f) ? v3 : 0.01f * v3;
      ushort4 o;
      o.x = ((mw >> (sh + 0)) & 1u) ? f2bf(v0 + v0) : (unsigned short)0;
      o.y = ((mw >> (sh + 1)) & 1u) ? f2bf(v1 + v1) : (unsigned short)0;
      o.z = ((mw >> (sh + 2)) & 1u) ? f2bf(v2 + v2) : (unsigned short)0;
      o.w = ((mw >> (sh + 3)) & 1u) ? f2bf(v3 + v3) : (unsigned short)0;
      *(ushort4*)(xout + (size_t)node * 128 + colb) = o;
    }
  }
}

// ---------------- Fused layer 3 + final projection ----------------------------
__global__ __launch_bounds__(256) void k_layer3_final(
    const unsigned short* __restrict__ xin,   // [NN][128] bf16
    const unsigned short* __restrict__ aggb,  // [NN][128] bf16
    const unsigned short* __restrict__ Wb,    // layer-3 [128][256], PRE-SWIZZLED
    const float* __restrict__ bias,           // [128] fp32
    const unsigned* __restrict__ mask,        // layer-3 dropout bits
    const unsigned short* __restrict__ Wob,   // [64][128] bf16 (linear)
    const float* __restrict__ bo,             // [64]
    float* __restrict__ out) {
  __shared__ unsigned short smem[16384];      // 32 KB: W halves, then act tile
  const int tid = threadIdx.x;
  const int lane = tid & 63;
  const int wv = tid >> 6;
  const int rbase = blockIdx.x * 64 + wv * 16;
  const int lr = lane & 15;
  const int lkq = lane >> 4;                  // 0..3
  const int rowg = lkq * 4;

  const f32x4* Wv = (const f32x4*)Wb;
  f32x4* dst = (f32x4*)smem;

  f32x4 acc[8];
#pragma unroll
  for (int j = 0; j < 8; ++j) acc[j] = (f32x4){0.f, 0.f, 0.f, 0.f};

  int n0 = rbase + lr;
  if (n0 >= NN) n0 = NN - 1;

  const char* WL = (const char*)smem;
#pragma unroll
  for (int half = 0; half < 2; ++half) {
    if (half) __syncthreads();
#pragma unroll
    for (int it = 0; it < 8; ++it) {
      const int c = it * 256 + tid;
      dst[c] = Wv[((c >> 4) << 5) + (half << 4) + (c & 15)];
    }
    __syncthreads();
    const unsigned short* A = half ? xin : aggb;
#pragma unroll
    for (int kfl = 0; kfl < 4; ++kfl) {
      const int kc = kfl * 32 + lkq * 8;
      s16x8 a0 = *(const s16x8*)(A + (size_t)n0 * 128 + kc);
#pragma unroll
      for (int nf = 0; nf < 8; ++nf) {
        const int row = nf * 16 + lr;
        const int bo2 = (row << 8) + ((((kfl << 6) + (lkq << 4)) ^ ((row & 7) << 4)));
        s16x8 wfr = *(const s16x8*)(WL + bo2);
        acc[nf] = __builtin_amdgcn_mfma_f32_16x16x32_bf16(wfr, a0, acc[nf], 0, 0, 0);
      }
    }
  }

  // epilogue -> act tile in LDS (reuse smem; W reads all complete after barrier)
  __syncthreads();
  {
    const int node = rbase + lr;
    const int nodec = (node < NN) ? node : (NN - 1);   // clamp for mask addressing
    const unsigned mbase = (unsigned)nodec * 4u;
    const int arow = wv * 16 + lr;                     // block-local act row
#pragma unroll
    for (int nf = 0; nf < 8; ++nf) {
      const int colb = nf * 16 + rowg;
      const float4 bv = *(const float4*)(bias + colb);
      const unsigned mw = mask[mbase + (colb >> 5)];
      const unsigned sh = (unsigned)(colb & 31);
      float v0 = acc[nf][0] + bv.x;
      float v1 = acc[nf][1] + bv.y;
      float v2 = acc[nf][2] + bv.z;
      float v3 = acc[nf][3] + bv.w;
      v0 = (v0 > 0.f) ? v0 : 0.01f * v0;
      v1 = (v1 > 0.f) ? v1 : 0.01f * v1;
      v2 = (v2 > 0.f) ? v2 : 0.01f * v2;
      v3 = (v3 > 0.f) ? v3 : 0.01f * v3;
      ushort4 o;
      o.x = ((mw >> (sh + 0)) & 1u) ? f2bf(v0 + v0) : (unsigned short)0;
      o.y = ((mw >> (sh + 1)) & 1u) ? f2bf(v1 + v1) : (unsigned short)0;
      o.z = ((mw >> (sh + 2)) & 1u) ? f2bf(v2 + v2) : (unsigned short)0;
      o.w = ((mw >> (sh + 3)) & 1u) ? f2bf(v3 + v3) : (unsigned short)0;
      *(ushort4*)(smem + arow * ALDS + colb) = o;
    }
  }
  __syncthreads();

  // final projection: each wave projects its own 16 rows from LDS
  f32x4 acc2[4];
#pragma unroll
  for (int j = 0; j < 4; ++j) acc2[j] = (f32x4){0.f, 0.f, 0.f, 0.f};

  const int arow = wv * 16 + lr;
#pragma unroll
  for (int kf = 0; kf < 4; ++kf) {
    const int kc = kf * 32 + lkq * 8;
    s16x8 a0 = *(const s16x8*)(smem + arow * ALDS + kc);
#pragma unroll
    for (int nf = 0; nf < 4; ++nf) {
      s16x8 wfr = *(const s16x8*)(Wob + (nf * 16 + lr) * 128 + kc);
      acc2[nf] = __builtin_amdgcn_mfma_f32_16x16x32_bf16(wfr, a0, acc2[nf], 0, 0, 0);
    }
  }

  const int node = rbase + lr;
  if (node < NN) {
#pragma unroll
    for (int nf = 0; nf < 4; ++nf) {
      const int colb = nf * 16 + rowg;
      const float4 bv = *(const float4*)(bo + colb);
      float4 o;
      o.x = acc2[nf][0] + bv.x;
      o.y = acc2[nf][1] + bv.y;
      o.z = acc2[nf][2] + bv.z;
      o.w = acc2[nf][3] + bv.w;
      *(float4*)(out + (size_t)node * 64 + colb) = o;
    }
  }
}

// ---------------- Host launch ----------------
extern "C" void kernel_launch(void* const* d_in, const int* in_sizes, int n_in,
                              void* d_out, int out_size, void* d_ws, size_t ws_size,
                              hipStream_t stream) {
  const float* x  = (const float*)d_in[0];
  const int*   ei = (const int*)d_in[1];
  const float* Wl = (const float*)d_in[2];
  const float* Wr = (const float*)d_in[3];
  const float* b  = (const float*)d_in[4];
  const float* Wo = (const float*)d_in[5];
  const float* bo = (const float*)d_in[6];
  float* out = (float*)d_out;

  char* wsp = (char*)d_ws;
  size_t off = 0;
  auto take = [&](size_t bytes) -> void* {
    off = (off + 255) & ~(size_t)255;
    void* p = wsp + off;
    off += bytes;
    return p;
  };
  unsigned short* xb0    = (unsigned short*)take((size_t)NN * 128 * 2);
  unsigned short* act1   = (unsigned short*)take((size_t)NN * 128 * 2);
  unsigned short* act2   = (unsigned short*)take((size_t)NN * 128 * 2);
  unsigned short* aggb   = (unsigned short*)take((size_t)NN * 128 * 2);
  unsigned short* Wb     = (unsigned short*)take((size_t)3 * 128 * 256 * 2);
  unsigned short* Wob    = (unsigned short*)take((size_t)OD * 128 * 2);
  unsigned*       masks  = (unsigned*)take((size_t)3 * WPL * 4);
  int*            bucket = (int*)take((size_t)NN * CAP * 4);
  int*            fill   = (int*)take((size_t)NN * 4);

  // ---- per-layer fold_in keys (host-side threefry: key(42) fold l) ----
  unsigned fk[3][2];
  for (int l = 0; l < 3; ++l) tf2x32(0u, 42u, 0u, (unsigned)l, fk[l][0], fk[l][1]);

  // ---- weight casts (+ fill zeroing) + single edge pass ----
  k_castw<<<(3 * 128 * 256 + OD * 128 + 255) / 256, 256, 0, stream>>>(Wl, Wr, Wo, Wb, Wob, fill);
  k_fill2<<<EE / 256, 256, 0, stream>>>(ei, fill, bucket,
                                        (unsigned long long*)(masks + WPL),
                                        fk[1][0], fk[1][1], x, xb0);

  // ---- layers (mask0 in agg#1, mask2 in agg#2; compile-time MCNT) ----
  const int gemmBlocks = (NN + 63) / 64;    // 1563
  const int aggBlocks  = 6250;              // 25000 waves, 4 nodes/wave, exact fit

  k_aggb<8><<<aggBlocks, 256, 0, stream>>>(xb0, bucket, fill, aggb,
                                           (unsigned long long*)masks,
                                           fk[0][0], fk[0][1]);
  k_layer_mfma<<<gemmBlocks, 256, 0, stream>>>(xb0, aggb, Wb, b, masks, act1);

  k_aggb<8><<<aggBlocks, 256, 0, stream>>>(act1, bucket, fill, aggb,
                                           (unsigned long long*)(masks + 2 * WPL),
                                           fk[2][0], fk[2][1]);
  k_layer_mfma<<<gemmBlocks, 256, 0, stream>>>(act1, aggb, Wb + 32768, b + 128,
                                               masks + WPL, act2);

  k_aggb<0><<<aggBlocks, 256, 0, stream>>>(act2, bucket, fill, aggb,
                                           (unsigned long long*)0, 0u, 0u);
  k_layer3_final<<<gemmBlocks, 256, 0, stream>>>(act2, aggb, Wb + 65536, b + 256,
                                                 masks + 2 * WPL, Wob, bo, out);

  (void)in_sizes; (void)n_in; (void)out_size; (void)ws_size;
}

// Round 19
// 270.476 us; speedup vs baseline: 1.0468x; 1.0055x over previous
//
#include <hip/hip_runtime.h>
#include <cstdint>
#include <cstddef>

// Problem constants (fixed by reference)
#define NN 100000          // nodes
#define EE 800000          // edges
#define HD 128             // hidden dim
#define OD 64              // out dim
#define CAP 64             // bucket capacity per node (P(deg>64) ~ 0 for Poisson(8))
#define WPL 400000         // dropout mask words per layer = NN*HD/32
#define ALDS 136           // padded act-tile stride (bf16 elems)
#define FS 16              // fill[] stride in ints (one counter per 64B cacheline)

typedef __attribute__((ext_vector_type(8))) short s16x8;
typedef __attribute__((ext_vector_type(4))) float f32x4;
typedef __attribute__((ext_vector_type(8))) unsigned short u16x8;

// RNE float -> bf16
__device__ __forceinline__ unsigned short f2bf(float f) {
  unsigned u = __float_as_uint(f);
  return (unsigned short)((u + 0x7FFFu + ((u >> 16) & 1u)) >> 16);
}
__device__ __forceinline__ float bf2f(unsigned short v) {
  return __uint_as_float(((unsigned)v) << 16);
}

__host__ __device__ __forceinline__ unsigned rotl32(unsigned x, int r) {
#ifdef __HIP_DEVICE_COMPILE__
  return __builtin_amdgcn_alignbit(x, x, 32 - r);  // (x<<r)|(x>>(32-r)), 1 instr
#else
  return (x << r) | (x >> (32 - r));
#endif
}

// ---------------- Threefry-2x32 (20 rounds), bit-exact vs JAX ----------------
__host__ __device__ __forceinline__ void tf2x32(unsigned k0, unsigned k1,
                                                unsigned x0, unsigned x1,
                                                unsigned& o0, unsigned& o1) {
  unsigned ks2 = k0 ^ k1 ^ 0x1BD11BDAu;
#define TFR(r) { x0 += x1; x1 = rotl32(x1, (r)) ^ x0; }
  x0 += k0; x1 += k1;
  TFR(13) TFR(15) TFR(26) TFR(6)
  x0 += k1; x1 += ks2 + 1u;
  TFR(17) TFR(29) TFR(16) TFR(24)
  x0 += ks2; x1 += k0 + 2u;
  TFR(13) TFR(15) TFR(26) TFR(6)
  x0 += k0; x1 += k1 + 3u;
  TFR(17) TFR(29) TFR(16) TFR(24)
  x0 += k1; x1 += ks2 + 4u;
  TFR(13) TFR(15) TFR(26) TFR(6)
  x0 += ks2; x1 += k0 + 5u;
#undef TFR
  o0 = x0; o1 = x1;
}

// 16 threefry+ballot -> one wave covers 1024 mask bits starting at wave*1024.
__device__ __forceinline__ void gen_mask_1024(unsigned long long* __restrict__ maskW,
                                              int wave, int lane,
                                              unsigned k0, unsigned k1) {
  const unsigned base = (unsigned)wave * 1024u + (unsigned)lane;
#pragma unroll
  for (int c = 0; c < 16; ++c) {
    unsigned r0, r1;
    tf2x32(k0, k1, 0u, base + (unsigned)(c << 6), r0, r1);
    unsigned long long m = __ballot(((r0 ^ r1) & 0x80000000u) == 0u);
    if (lane == 0) maskW[wave * 16 + c] = m;
  }
}

// cast 8 fp32 -> 8 bf16 at flat chunk t (elems [t*8, t*8+8))
__device__ __forceinline__ void cast8(const float* __restrict__ x,
                                      unsigned short* __restrict__ xb, int t) {
  const float4* p = (const float4*)x + (size_t)t * 2;
  float4 v0 = p[0], v1 = p[1];
  u16x8 r;
  r[0] = f2bf(v0.x); r[1] = f2bf(v0.y); r[2] = f2bf(v0.z); r[3] = f2bf(v0.w);
  r[4] = f2bf(v1.x); r[5] = f2bf(v1.y); r[6] = f2bf(v1.z); r[7] = f2bf(v1.w);
  *((u16x8*)xb + t) = r;
}

// ---------------- Weight casts + padded-fill zeroing ---------------------------
// Wb pre-swizzled: elem' = elem ^ ((row&7)<<3)  (byte ^= (row&7)<<4)
__global__ __launch_bounds__(256) void k_castw(const float* __restrict__ Wl,
                                               const float* __restrict__ Wr,
                                               const float* __restrict__ Wo,
                                               unsigned short* __restrict__ Wb,
                                               unsigned short* __restrict__ Wob,
                                               int* __restrict__ fill) {
  int t = blockIdx.x * 256 + threadIdx.x;
  if (t < NN) fill[t * FS] = 0;
  if (t < 3 * 128 * 256) {
    int l = t >> 15;
    int rem = t & 32767;
    int n = rem >> 8;
    int k = rem & 255;
    float w = (k < 128) ? Wl[(l << 14) + (n << 7) + k] : Wr[(l << 14) + (n << 7) + (k - 128)];
    int sw = rem ^ ((n & 7) << 3);
    Wb[(l << 15) + sw] = f2bf(w);
  } else {
    int t3 = t - 3 * 128 * 256;
    if (t3 < OD * 128) Wob[t3] = f2bf(Wo[t3]);
  }
}

// ---------------- Single edge pass: bucket fill + x-cast + mask1 --------------
// exact grid 3125 x 256 = 800000 (ballot needs all lanes active).
// fill[] padded to 1 counter / 64B line: drops same-line atomic contention 16x
// (was ~128 atomics per line on the packed array).
__global__ __launch_bounds__(256) void k_fill2(const int* __restrict__ ei,
                                               int* __restrict__ fill,
                                               int* __restrict__ bucket,
                                               unsigned long long* __restrict__ mask1,
                                               unsigned mk0, unsigned mk1,
                                               const float* __restrict__ x,
                                               unsigned short* __restrict__ xb) {
  const int e = blockIdx.x * 256 + threadIdx.x;   // < EE always
  unsigned s = (unsigned)ei[e];
  unsigned d = (unsigned)ei[EE + e];
  if (s >= NN) s = 0;
  if (d >= NN) d = 0;
  int p = atomicAdd(&fill[d * FS], 1);             // issue early...
  cast8(x, xb, e);                                 // elems [0, 6.4M)
  cast8(x, xb, EE + e);                            // elems [6.4M, 12.8M)
  gen_mask_1024(mask1, e >> 6, e & 63, mk0, mk1);
  if (p < CAP) bucket[d * CAP + p] = (int)s;       // ...consume late
}

// ---------------- Mean aggregation from buckets (+ compile-time mask gen) -----
// QUARTER-wave per node (4 nodes/wave, 25000 waves), 16B u16x8 gathers,
// 4 streams in flight per quarter (16/wave), VGPR < 64. MCNT compile-time
// so the threefry chains unroll and interleave.
template<int MCNT>
__global__ __launch_bounds__(256) void k_aggb(const unsigned short* __restrict__ xb,
                                              const int* __restrict__ bucket,
                                              const int* __restrict__ fill,
                                              unsigned short* __restrict__ aggb,
                                              unsigned long long* __restrict__ maskW,
                                              unsigned mk0, unsigned mk1) {
  const int w = (blockIdx.x * 256 + threadIdx.x) >> 6;  // wave 0..24999
  const int lane = threadIdx.x & 63;
  const int q = lane >> 4;        // quarter 0..3
  const int ql = lane & 15;       // lane within quarter (col slice)
  const int qb = q << 4;
  const int n = (w << 2) + q;     // node, < 100000 always

  const int degf = fill[n * FS];
  const int deg = (degf < CAP) ? degf : CAP;
  int idx = (ql < deg) ? bucket[n * CAP + ql] : 0;  // first 16 bucket entries
  const float sc = (degf > 0) ? 1.0f / (float)degf : 0.0f;  // IEEE div, matches ref

  if (MCNT > 0) {
    const unsigned base = (unsigned)w * 512u + (unsigned)lane;
#pragma unroll
    for (int c = 0; c < MCNT; ++c) {
      unsigned r0, r1;
      tf2x32(mk0, mk1, 0u, base + (unsigned)(c << 6), r0, r1);
      unsigned long long m = __ballot(((r0 ^ r1) & 0x80000000u) == 0u);
      if (lane == 0) maskW[(w << 3) + c] = m;
    }
  }

  const u16x8* xb8 = (const u16x8*)xb;   // row = 16 x u16x8
  float a0[8], a1[8], a2[8], a3[8];
#pragma unroll
  for (int k = 0; k < 8; ++k) { a0[k] = 0.f; a1[k] = 0.f; a2[k] = 0.f; a3[k] = 0.f; }

  const int dcap = (deg < 16) ? deg : 16;
  int i0 = 0;
  for (; i0 + 4 <= dcap; i0 += 4) {  // 4 gathers in flight per quarter
    int j0 = __shfl(idx, qb + i0);
    int j1 = __shfl(idx, qb + i0 + 1);
    int j2 = __shfl(idx, qb + i0 + 2);
    int j3 = __shfl(idx, qb + i0 + 3);
    u16x8 v0 = xb8[(size_t)j0 * 16 + ql];
    u16x8 v1 = xb8[(size_t)j1 * 16 + ql];
    u16x8 v2 = xb8[(size_t)j2 * 16 + ql];
    u16x8 v3 = xb8[(size_t)j3 * 16 + ql];
#pragma unroll
    for (int k = 0; k < 8; ++k) {
      a0[k] += bf2f(v0[k]); a1[k] += bf2f(v1[k]);
      a2[k] += bf2f(v2[k]); a3[k] += bf2f(v3[k]);
    }
  }
  // remainder (up to 3), guarded per-stream (exec-masked, loads still overlap)
  {
    const int rem = dcap - i0;
    int j0 = __shfl(idx, qb + (i0 & 15));
    int j1 = __shfl(idx, qb + ((i0 + 1) & 15));
    int j2 = __shfl(idx, qb + ((i0 + 2) & 15));
    if (rem > 0) {
      u16x8 v = xb8[(size_t)j0 * 16 + ql];
#pragma unroll
      for (int k = 0; k < 8; ++k) a0[k] += bf2f(v[k]);
    }
    if (rem > 1) {
      u16x8 v = xb8[(size_t)j1 * 16 + ql];
#pragma unroll
      for (int k = 0; k < 8; ++k) a1[k] += bf2f(v[k]);
    }
    if (rem > 2) {
      u16x8 v = xb8[(size_t)j2 * 16 + ql];
#pragma unroll
      for (int k = 0; k < 8; ++k) a2[k] += bf2f(v[k]);
    }
  }
  // deg in (16, 64]: uniform-address loads per quarter (~0.3% of nodes)
  for (int i = 16; i < deg; ++i) {
    int sX = bucket[n * CAP + i];
    u16x8 v = xb8[(size_t)sX * 16 + ql];
#pragma unroll
    for (int k = 0; k < 8; ++k) a3[k] += bf2f(v[k]);
  }

  u16x8 o;
#pragma unroll
  for (int k = 0; k < 8; ++k)
    o[k] = f2bf(((a0[k] + a1[k]) + (a2[k] + a3[k])) * sc);
  ((u16x8*)aggb)[(size_t)n * 16 + ql] = o;
}

// ---------------- Layer: bf16 MFMA GEMM, W staged in two 32KB LDS halves ------
// 64 rows/block (1563 blocks), 4 waves x 16 rows. LDS = 32KB -> ~5 blocks/CU.
__global__ __launch_bounds__(256) void k_layer_mfma(
    const unsigned short* __restrict__ xin,   // [NN][128] bf16
    const unsigned short* __restrict__ aggb,  // [NN][128] bf16
    const unsigned short* __restrict__ Wb,    // [128][256] bf16, PRE-SWIZZLED
    const float* __restrict__ bias,           // [128] fp32
    const unsigned* __restrict__ mask,        // this layer's dropout bits
    unsigned short* __restrict__ xout) {
  __shared__ unsigned short Wlds[16384];      // 32 KB
  const int tid = threadIdx.x;
  const int lane = tid & 63;
  const int wv = tid >> 6;
  const int rbase = blockIdx.x * 64 + wv * 16;
  const int lr = lane & 15;
  const int lkq = lane >> 4;                  // 0..3
  const int rowg = lkq * 4;

  const f32x4* Wv = (const f32x4*)Wb;
  f32x4* dst = (f32x4*)Wlds;

  f32x4 acc[8];
#pragma unroll
  for (int j = 0; j < 8; ++j) acc[j] = (f32x4){0.f, 0.f, 0.f, 0.f};

  int n0 = rbase + lr;
  if (n0 >= NN) n0 = NN - 1;

  const char* WL = (const char*)Wlds;
#pragma unroll
  for (int half = 0; half < 2; ++half) {
    if (half) __syncthreads();   // all waves done reading previous half
#pragma unroll
    for (int it = 0; it < 8; ++it) {
      const int c = it * 256 + tid;
      dst[c] = Wv[((c >> 4) << 5) + (half << 4) + (c & 15)];
    }
    __syncthreads();
    const unsigned short* A = half ? xin : aggb;
#pragma unroll
    for (int kfl = 0; kfl < 4; ++kfl) {
      const int kc = kfl * 32 + lkq * 8;
      s16x8 a0 = *(const s16x8*)(A + (size_t)n0 * 128 + kc);
#pragma unroll
      for (int nf = 0; nf < 8; ++nf) {
        const int row = nf * 16 + lr;
        const int bo = (row << 8) + ((((kfl << 6) + (lkq << 4)) ^ ((row & 7) << 4)));
        s16x8 wfr = *(const s16x8*)(WL + bo);
        acc[nf] = __builtin_amdgcn_mfma_f32_16x16x32_bf16(wfr, a0, acc[nf], 0, 0, 0);
      }
    }
  }

  const int node = rbase + lr;
  if (node < NN) {
    const unsigned mbase = (unsigned)node * 4u;
#pragma unroll
    for (int nf = 0; nf < 8; ++nf) {
      const int colb = nf * 16 + rowg;
      const float4 bv = *(const float4*)(bias + colb);
      const unsigned mw = mask[mbase + (colb >> 5)];
      const unsigned sh = (unsigned)(colb & 31);
      float v0 = acc[nf][0] + bv.x;
      float v1 = acc[nf][1] + bv.y;
      float v2 = acc[nf][2] + bv.z;
      float v3 = acc[nf][3] + bv.w;
      v0 = (v0 > 0.f) ? v0 : 0.01f * v0;
      v1 = (v1 > 0.f) ? v1 : 0.01f * v1;
      v2 = (v2 > 0.f) ? v2 : 0.01f * v2;
      v3 = (v3 > 0.f) ? v3 : 0.01f * v3;
      ushort4 o;
      o.x = ((mw >> (sh + 0)) & 1u) ? f2bf(v0 + v0) : (unsigned short)0;
      o.y = ((mw >> (sh + 1)) & 1u) ? f2bf(v1 + v1) : (unsigned short)0;
      o.z = ((mw >> (sh + 2)) & 1u) ? f2bf(v2 + v2) : (unsigned short)0;
      o.w = ((mw >> (sh + 3)) & 1u) ? f2bf(v3 + v3) : (unsigned short)0;
      *(ushort4*)(xout + (size_t)node * 128 + colb) = o;
    }
  }
}

// ---------------- Fused layer 3 + final projection ----------------------------
__global__ __launch_bounds__(256) void k_layer3_final(
    const unsigned short* __restrict__ xin,   // [NN][128] bf16
    const unsigned short* __restrict__ aggb,  // [NN][128] bf16
    const unsigned short* __restrict__ Wb,    // layer-3 [128][256], PRE-SWIZZLED
    const float* __restrict__ bias,           // [128] fp32
    const unsigned* __restrict__ mask,        // layer-3 dropout bits
    const unsigned short* __restrict__ Wob,   // [64][128] bf16 (linear)
    const float* __restrict__ bo,             // [64]
    float* __restrict__ out) {
  __shared__ unsigned short smem[16384];      // 32 KB: W halves, then act tile
  const int tid = threadIdx.x;
  const int lane = tid & 63;
  const int wv = tid >> 6;
  const int rbase = blockIdx.x * 64 + wv * 16;
  const int lr = lane & 15;
  const int lkq = lane >> 4;                  // 0..3
  const int rowg = lkq * 4;

  const f32x4* Wv = (const f32x4*)Wb;
  f32x4* dst = (f32x4*)smem;

  f32x4 acc[8];
#pragma unroll
  for (int j = 0; j < 8; ++j) acc[j] = (f32x4){0.f, 0.f, 0.f, 0.f};

  int n0 = rbase + lr;
  if (n0 >= NN) n0 = NN - 1;

  const char* WL = (const char*)smem;
#pragma unroll
  for (int half = 0; half < 2; ++half) {
    if (half) __syncthreads();
#pragma unroll
    for (int it = 0; it < 8; ++it) {
      const int c = it * 256 + tid;
      dst[c] = Wv[((c >> 4) << 5) + (half << 4) + (c & 15)];
    }
    __syncthreads();
    const unsigned short* A = half ? xin : aggb;
#pragma unroll
    for (int kfl = 0; kfl < 4; ++kfl) {
      const int kc = kfl * 32 + lkq * 8;
      s16x8 a0 = *(const s16x8*)(A + (size_t)n0 * 128 + kc);
#pragma unroll
      for (int nf = 0; nf < 8; ++nf) {
        const int row = nf * 16 + lr;
        const int bo2 = (row << 8) + ((((kfl << 6) + (lkq << 4)) ^ ((row & 7) << 4)));
        s16x8 wfr = *(const s16x8*)(WL + bo2);
        acc[nf] = __builtin_amdgcn_mfma_f32_16x16x32_bf16(wfr, a0, acc[nf], 0, 0, 0);
      }
    }
  }

  // epilogue -> act tile in LDS (reuse smem; W reads all complete after barrier)
  __syncthreads();
  {
    const int node = rbase + lr;
    const int nodec = (node < NN) ? node : (NN - 1);   // clamp for mask addressing
    const unsigned mbase = (unsigned)nodec * 4u;
    const int arow = wv * 16 + lr;                     // block-local act row
#pragma unroll
    for (int nf = 0; nf < 8; ++nf) {
      const int colb = nf * 16 + rowg;
      const float4 bv = *(const float4*)(bias + colb);
      const unsigned mw = mask[mbase + (colb >> 5)];
      const unsigned sh = (unsigned)(colb & 31);
      float v0 = acc[nf][0] + bv.x;
      float v1 = acc[nf][1] + bv.y;
      float v2 = acc[nf][2] + bv.z;
      float v3 = acc[nf][3] + bv.w;
      v0 = (v0 > 0.f) ? v0 : 0.01f * v0;
      v1 = (v1 > 0.f) ? v1 : 0.01f * v1;
      v2 = (v2 > 0.f) ? v2 : 0.01f * v2;
      v3 = (v3 > 0.f) ? v3 : 0.01f * v3;
      ushort4 o;
      o.x = ((mw >> (sh + 0)) & 1u) ? f2bf(v0 + v0) : (unsigned short)0;
      o.y = ((mw >> (sh + 1)) & 1u) ? f2bf(v1 + v1) : (unsigned short)0;
      o.z = ((mw >> (sh + 2)) & 1u) ? f2bf(v2 + v2) : (unsigned short)0;
      o.w = ((mw >> (sh + 3)) & 1u) ? f2bf(v3 + v3) : (unsigned short)0;
      *(ushort4*)(smem + arow * ALDS + colb) = o;
    }
  }
  __syncthreads();

  // final projection: each wave projects its own 16 rows from LDS
  f32x4 acc2[4];
#pragma unroll
  for (int j = 0; j < 4; ++j) acc2[j] = (f32x4){0.f, 0.f, 0.f, 0.f};

  const int arow = wv * 16 + lr;
#pragma unroll
  for (int kf = 0; kf < 4; ++kf) {
    const int kc = kf * 32 + lkq * 8;
    s16x8 a0 = *(const s16x8*)(smem + arow * ALDS + kc);
#pragma unroll
    for (int nf = 0; nf < 4; ++nf) {
      s16x8 wfr = *(const s16x8*)(Wob + (nf * 16 + lr) * 128 + kc);
      acc2[nf] = __builtin_amdgcn_mfma_f32_16x16x32_bf16(wfr, a0, acc2[nf], 0, 0, 0);
    }
  }

  const int node = rbase + lr;
  if (node < NN) {
#pragma unroll
    for (int nf = 0; nf < 4; ++nf) {
      const int colb = nf * 16 + rowg;
      const float4 bv = *(const float4*)(bo + colb);
      float4 o;
      o.x = acc2[nf][0] + bv.x;
      o.y = acc2[nf][1] + bv.y;
      o.z = acc2[nf][2] + bv.z;
      o.w = acc2[nf][3] + bv.w;
      *(float4*)(out + (size_t)node * 64 + colb) = o;
    }
  }
}

// ---------------- Host launch ----------------
extern "C" void kernel_launch(void* const* d_in, const int* in_sizes, int n_in,
                              void* d_out, int out_size, void* d_ws, size_t ws_size,
                              hipStream_t stream) {
  const float* x  = (const float*)d_in[0];
  const int*   ei = (const int*)d_in[1];
  const float* Wl = (const float*)d_in[2];
  const float* Wr = (const float*)d_in[3];
  const float* b  = (const float*)d_in[4];
  const float* Wo = (const float*)d_in[5];
  const float* bo = (const float*)d_in[6];
  float* out = (float*)d_out;

  char* wsp = (char*)d_ws;
  size_t off = 0;
  auto take = [&](size_t bytes) -> void* {
    off = (off + 255) & ~(size_t)255;
    void* p = wsp + off;
    off += bytes;
    return p;
  };
  unsigned short* xb0    = (unsigned short*)take((size_t)NN * 128 * 2);
  unsigned short* act1   = (unsigned short*)take((size_t)NN * 128 * 2);
  unsigned short* act2   = (unsigned short*)take((size_t)NN * 128 * 2);
  unsigned short* aggb   = (unsigned short*)take((size_t)NN * 128 * 2);
  unsigned short* Wb     = (unsigned short*)take((size_t)3 * 128 * 256 * 2);
  unsigned short* Wob    = (unsigned short*)take((size_t)OD * 128 * 2);
  unsigned*       masks  = (unsigned*)take((size_t)3 * WPL * 4);
  int*            bucket = (int*)take((size_t)NN * CAP * 4);
  int*            fill   = (int*)take((size_t)NN * FS * 4);   // padded: 1 int / 64B line

  // ---- per-layer fold_in keys (host-side threefry: key(42) fold l) ----
  unsigned fk[3][2];
  for (int l = 0; l < 3; ++l) tf2x32(0u, 42u, 0u, (unsigned)l, fk[l][0], fk[l][1]);

  // ---- weight casts (+ fill zeroing) + single edge pass ----
  k_castw<<<(3 * 128 * 256 + OD * 128 + 255) / 256, 256, 0, stream>>>(Wl, Wr, Wo, Wb, Wob, fill);
  k_fill2<<<EE / 256, 256, 0, stream>>>(ei, fill, bucket,
                                        (unsigned long long*)(masks + WPL),
                                        fk[1][0], fk[1][1], x, xb0);

  // ---- layers (mask0 in agg#1, mask2 in agg#2; compile-time MCNT) ----
  const int gemmBlocks = (NN + 63) / 64;    // 1563
  const int aggBlocks  = 6250;              // 25000 waves, 4 nodes/wave, exact fit

  k_aggb<8><<<aggBlocks, 256, 0, stream>>>(xb0, bucket, fill, aggb,
                                           (unsigned long long*)masks,
                                           fk[0][0], fk[0][1]);
  k_layer_mfma<<<gemmBlocks, 256, 0, stream>>>(xb0, aggb, Wb, b, masks, act1);

  k_aggb<8><<<aggBlocks, 256, 0, stream>>>(act1, bucket, fill, aggb,
                                           (unsigned long long*)(masks + 2 * WPL),
                                           fk[2][0], fk[2][1]);
  k_layer_mfma<<<gemmBlocks, 256, 0, stream>>>(act1, aggb, Wb + 32768, b + 128,
                                               masks + WPL, act2);

  k_aggb<0><<<aggBlocks, 256, 0, stream>>>(act2, bucket, fill, aggb,
                                           (unsigned long long*)0, 0u, 0u);
  k_layer3_final<<<gemmBlocks, 256, 0, stream>>>(act2, aggb, Wb + 65536, b + 256,
                                                 masks + 2 * WPL, Wob, bo, out);

  (void)in_sizes; (void)n_in; (void)out_size; (void)ws_size;
}